// Round 1
// baseline (894.147 us; speedup 1.0000x reference)
//
#include <hip/hip_runtime.h>
#include <hip/hip_bf16.h>

typedef float f32x4 __attribute__((ext_vector_type(4)));
typedef unsigned short u16;
typedef unsigned short u16x4 __attribute__((ext_vector_type(4)));
typedef unsigned short u16x8 __attribute__((ext_vector_type(8)));

#define NEG_MAX (-3.4028234663852886e38f)
#define NODE_SCALE 0.125f
#define EDGE_SCALE 0.70710678118654752f

__device__ __forceinline__ float bf2f(u16 u) {
  unsigned int w = ((unsigned int)u) << 16;
  return __builtin_bit_cast(float, w);
}
__device__ __forceinline__ u16 f2bf(float f) {
  unsigned int x = __builtin_bit_cast(unsigned int, f);
  x = x + 0x7FFFu + ((x >> 16) & 1u);
  return (u16)(x >> 16);
}

// ---------------- kernel M: normalize mask to float 0/1 (dtype-robust) ----
__global__ void mask_norm(const unsigned char* __restrict__ mraw,
                          float* __restrict__ mask_f) {
  __shared__ int flags;
  int t = threadIdx.x;
  if (t == 0) flags = 0;
  __syncthreads();
  const unsigned int* mu = (const unsigned int*)mraw;
  int f = 0;
  for (int e = t; e < 512; e += 256) { if (mu[e] > 1u) f |= 1; }       // not int32 0/1
  for (int e = t; e < 2048; e += 256) { if (mraw[e] > 1) f |= 2; }     // not packed bytes
  if (f) atomicOr(&flags, f);
  __syncthreads();
  int fl = flags;
  for (int e = t; e < 2048; e += 256) {
    float v;
    if (!(fl & 1))      v = (mu[e] != 0u) ? 1.f : 0.f;                 // int32
    else if (!(fl & 2)) v = (mraw[e] != 0) ? 1.f : 0.f;                // bool bytes
    else                v = (((const float*)mraw)[e] != 0.f) ? 1.f : 0.f; // float
    mask_f[e] = v;
  }
}

// ---------------- kernel A: qkv projection + rotary ----------------------
__global__ __launch_bounds__(256) void qkv_rope(
    const float* __restrict__ node, const float* __restrict__ Wq,
    const float* __restrict__ Wk, const float* __restrict__ Wv,
    float* __restrict__ qw, u16* __restrict__ kwb, u16* __restrict__ vwb) {
  __shared__ __align__(16) float xs[8 * 256];
  int t = threadIdx.x;
  int row0 = blockIdx.x * 8;
#pragma unroll
  for (int p = 0; p < 2; ++p) {
    int f = p * 256 + t;
    *(f32x4*)(&xs[f * 4]) = *(const f32x4*)(node + (size_t)row0 * 256 + f * 4);
  }
  __syncthreads();
  float qa[8], ka[8], va[8];
#pragma unroll
  for (int r = 0; r < 8; ++r) { qa[r] = 0.f; ka[r] = 0.f; va[r] = 0.f; }
  for (int c = 0; c < 256; ++c) {
    float wq = Wq[c * 256 + t];
    float wk = Wk[c * 256 + t];
    float wv = Wv[c * 256 + t];
#pragma unroll
    for (int r = 0; r < 8; ++r) {
      float x = xs[r * 256 + c];
      qa[r] += x * wq; ka[r] += x * wk; va[r] += x * wv;
    }
  }
  int h = t >> 5, d = t & 31;
  float inv = powf(10000.f, -((float)(2 * (d >> 1)) * (1.f / 32.f)));
#pragma unroll
  for (int r = 0; r < 8; ++r) {
    int gr = row0 + r;
    int b = gr >> 10, i = gr & 1023;
    float ang = (float)i * inv;
    float sn, cs;
    sincosf(ang, &sn, &cs);
    float qp = __shfl_xor(qa[r], 1, 64);
    float kp = __shfl_xor(ka[r], 1, 64);
    float qo = (d & 1) ? (qp * sn + qa[r] * cs) : (qa[r] * cs - qp * sn);
    float ko = (d & 1) ? (kp * sn + ka[r] * cs) : (ka[r] * cs - kp * sn);
    int idx = ((b * 8 + h) * 1024 + i) * 32 + d;
    qw[idx] = qo;
    kwb[idx] = f2bf(ko);
    vwb[idx] = f2bf(va[r]);
  }
}

// ---------------- kernel B: fused attention (single pass over edge) ------
__global__ __launch_bounds__(256) void attn_fused(
    const float* __restrict__ edge, const float* __restrict__ qw,
    const u16* __restrict__ kwb, const u16* __restrict__ vwb,
    const float* __restrict__ We, const float* __restrict__ be,
    const float* __restrict__ mask_f, float* __restrict__ rescat) {
  __shared__ __align__(16) u16 Eb[64 * 64];   // row-major (j,d), bf16, xor-swizzled
  __shared__ __align__(16) u16 ETb[64 * 64];  // transposed (d,j), bf16, xor-swizzled
  __shared__ __align__(16) float Lg[8][64];   // logits -> p (fp32)
  __shared__ __align__(16) float WesT[8][64]; // We transposed [h][d]
  __shared__ __align__(16) float qs[256];     // q[h][d] for this i
  __shared__ float bes[8];
  __shared__ float mS[8], sS[8], rS[8];

  int bid = blockIdx.x;
  int xcd = bid & 7, slot = bid >> 3;
  int b = xcd >> 2;
  int i = (xcd & 3) * 256 + slot;
  int t = threadIdx.x;
  int lane = t & 63;
  int wave = __builtin_amdgcn_readfirstlane(t >> 6);

  // staging: q row, We^T, be, softmax state
  {
    int h = t >> 5, d = t & 31;
    qs[t] = qw[((b * 8 + h) * 1024 + i) * 32 + d];
  }
#pragma unroll
  for (int p = 0; p < 2; ++p) {
    int e = p * 256 + t;
    WesT[e & 7][e >> 3] = We[e];
  }
  if (t < 8) { bes[t] = be[t]; mS[t] = NEG_MAX; sS[t] = 0.f; rS[t] = 1.f; }

  float mi = mask_f[b * 1024 + i];
  const float* ebase = edge + ((size_t)(b * 1024 + i)) * (1024 * 64);

  f32x4 acc_v = {0.f, 0.f, 0.f, 0.f};
  float acc_e0 = 0.f, acc_e1 = 0.f;
  int h3a = t >> 5, dq3a = (t >> 2) & 7, rep3a = t & 3;

  __syncthreads();

  for (int j0 = 0; j0 < 1024; j0 += 64) {
    // ---- phase 0: stream edge tile -> LDS (bf16, dual layout), nontemporal
#pragma unroll
    for (int p = 0; p < 4; ++p) {
      int e = p * 1024 + t * 4;
      int j = e >> 6, d0 = e & 63;
      f32x4 v = __builtin_nontemporal_load(
          (const f32x4*)(ebase + (size_t)(j0 + j) * 64 + d0));
      u16 b0 = f2bf(v.x), b1 = f2bf(v.y), b2 = f2bf(v.z), b3 = f2bf(v.w);
      int g = d0 >> 3;
      int posE = j * 64 + ((g ^ (j & 7)) << 3) + (d0 & 7);
      u16x4 pk = {b0, b1, b2, b3};
      *(u16x4*)(&Eb[posE]) = pk;
      int jg = j >> 3, jr = j & 7;
      ETb[(d0 + 0) * 64 + ((jg ^ ((d0 + 0) & 7)) << 3) + jr] = b0;
      ETb[(d0 + 1) * 64 + ((jg ^ ((d0 + 1) & 7)) << 3) + jr] = b1;
      ETb[(d0 + 2) * 64 + ((jg ^ ((d0 + 2) & 7)) << 3) + jr] = b2;
      ETb[(d0 + 3) * 64 + ((jg ^ ((d0 + 3) & 7)) << 3) + jr] = b3;
    }
    __syncthreads();

    // ---- phase 1: logits for heads (wave, wave+4), column j = lane ------
    {
      int h1 = wave, h2 = wave + 4;
      int j = lane;
      int sw = j & 7;
      float bias1 = 0.f, bias2 = 0.f;
#pragma unroll
      for (int gl = 0; gl < 8; ++gl) {
        u16x8 eu = *(const u16x8*)(&Eb[j * 64 + ((gl ^ sw) << 3)]);
        f32x4 w1a = *(const f32x4*)(&WesT[h1][gl * 8]);
        f32x4 w1b = *(const f32x4*)(&WesT[h1][gl * 8 + 4]);
        f32x4 w2a = *(const f32x4*)(&WesT[h2][gl * 8]);
        f32x4 w2b = *(const f32x4*)(&WesT[h2][gl * 8 + 4]);
        bias1 += bf2f(eu[0]) * w1a.x + bf2f(eu[1]) * w1a.y + bf2f(eu[2]) * w1a.z + bf2f(eu[3]) * w1a.w
               + bf2f(eu[4]) * w1b.x + bf2f(eu[5]) * w1b.y + bf2f(eu[6]) * w1b.z + bf2f(eu[7]) * w1b.w;
        bias2 += bf2f(eu[0]) * w2a.x + bf2f(eu[1]) * w2a.y + bf2f(eu[2]) * w2a.z + bf2f(eu[3]) * w2a.w
               + bf2f(eu[4]) * w2b.x + bf2f(eu[5]) * w2b.y + bf2f(eu[6]) * w2b.z + bf2f(eu[7]) * w2b.w;
      }
      float qk1 = 0.f, qk2 = 0.f;
      const u16* kr1 = kwb + ((b * 8 + h1) * 1024 + j0 + j) * 32;
      const u16* kr2 = kwb + ((b * 8 + h2) * 1024 + j0 + j) * 32;
#pragma unroll
      for (int g = 0; g < 4; ++g) {
        u16x8 k1 = *(const u16x8*)(kr1 + g * 8);
        u16x8 k2 = *(const u16x8*)(kr2 + g * 8);
        f32x4 q1a = *(const f32x4*)(&qs[h1 * 32 + g * 8]);
        f32x4 q1b = *(const f32x4*)(&qs[h1 * 32 + g * 8 + 4]);
        f32x4 q2a = *(const f32x4*)(&qs[h2 * 32 + g * 8]);
        f32x4 q2b = *(const f32x4*)(&qs[h2 * 32 + g * 8 + 4]);
        qk1 += bf2f(k1[0]) * q1a.x + bf2f(k1[1]) * q1a.y + bf2f(k1[2]) * q1a.z + bf2f(k1[3]) * q1a.w
             + bf2f(k1[4]) * q1b.x + bf2f(k1[5]) * q1b.y + bf2f(k1[6]) * q1b.z + bf2f(k1[7]) * q1b.w;
        qk2 += bf2f(k2[0]) * q2a.x + bf2f(k2[1]) * q2a.y + bf2f(k2[2]) * q2a.z + bf2f(k2[3]) * q2a.w
             + bf2f(k2[4]) * q2b.x + bf2f(k2[5]) * q2b.y + bf2f(k2[6]) * q2b.z + bf2f(k2[7]) * q2b.w;
      }
      bool pm = (mi != 0.f) && (mask_f[b * 1024 + j0 + j] != 0.f);
      float l1 = pm ? (NODE_SCALE * qk1 + EDGE_SCALE * (bias1 + bes[h1])) : NEG_MAX;
      float l2 = pm ? (NODE_SCALE * qk2 + EDGE_SCALE * (bias2 + bes[h2])) : NEG_MAX;
      Lg[h1][j] = l1;
      Lg[h2][j] = l2;
    }
    __syncthreads();

    // ---- phase 2: online softmax update (per-wave: heads wave, wave+4) --
#pragma unroll
    for (int hh = 0; hh < 2; ++hh) {
      int h = wave + hh * 4;
      float x = Lg[h][lane];
      float mx = x;
#pragma unroll
      for (int off = 32; off > 0; off >>= 1) mx = fmaxf(mx, __shfl_xor(mx, off, 64));
      float mo = mS[h];
      float mn = fmaxf(mo, mx);
      float p = __expf(x - mn);
      float ps = p;
#pragma unroll
      for (int off = 32; off > 0; off >>= 1) ps += __shfl_xor(ps, off, 64);
      Lg[h][lane] = p;
      if (lane == 0) {
        float r = __expf(mo - mn);
        mS[h] = mn; rS[h] = r; sS[h] = sS[h] * r + ps;
      }
    }
    __syncthreads();

    // ---- phase 3a: acc_v  (thread owns h, d-quad; rep splits j range) ---
    {
      float r = rS[h3a];
      const u16* vb = vwb + ((b * 8 + h3a) * 1024 + j0 + rep3a * 16) * 32 + dq3a * 4;
      f32x4 s = {0.f, 0.f, 0.f, 0.f};
#pragma unroll
      for (int x = 0; x < 16; ++x) {
        float p = Lg[h3a][rep3a * 16 + x];
        u16x4 vv = *(const u16x4*)(vb + x * 32);
        s.x += p * bf2f(vv[0]);
        s.y += p * bf2f(vv[1]);
        s.z += p * bf2f(vv[2]);
        s.w += p * bf2f(vv[3]);
      }
      acc_v.x = acc_v.x * r + s.x;
      acc_v.y = acc_v.y * r + s.y;
      acc_v.z = acc_v.z * r + s.z;
      acc_v.w = acc_v.w * r + s.w;
    }
    // ---- phase 3b: acc_e (thread owns heads (wave,wave+4), column d2) ---
    {
      int h1 = wave, h2 = wave + 4;
      float r1 = rS[h1], r2 = rS[h2];
      int d2 = lane;
      int sw2 = d2 & 7;
      float s1 = 0.f, s2 = 0.f;
#pragma unroll
      for (int gl = 0; gl < 8; ++gl) {
        u16x8 eu = *(const u16x8*)(&ETb[d2 * 64 + ((gl ^ sw2) << 3)]);
        f32x4 pa = *(const f32x4*)(&Lg[h1][gl * 8]);
        f32x4 pb = *(const f32x4*)(&Lg[h1][gl * 8 + 4]);
        f32x4 pc = *(const f32x4*)(&Lg[h2][gl * 8]);
        f32x4 pd = *(const f32x4*)(&Lg[h2][gl * 8 + 4]);
        s1 += bf2f(eu[0]) * pa.x + bf2f(eu[1]) * pa.y + bf2f(eu[2]) * pa.z + bf2f(eu[3]) * pa.w
            + bf2f(eu[4]) * pb.x + bf2f(eu[5]) * pb.y + bf2f(eu[6]) * pb.z + bf2f(eu[7]) * pb.w;
        s2 += bf2f(eu[0]) * pc.x + bf2f(eu[1]) * pc.y + bf2f(eu[2]) * pc.z + bf2f(eu[3]) * pc.w
            + bf2f(eu[4]) * pd.x + bf2f(eu[5]) * pd.y + bf2f(eu[6]) * pd.z + bf2f(eu[7]) * pd.w;
      }
      acc_e0 = acc_e0 * r1 + s1;
      acc_e1 = acc_e1 * r2 + s2;
    }
    __syncthreads();
  }

  // ---- epilogue: reduce acc_v over rep groups, normalize, write rescat --
  float* red = (float*)Eb;  // 4 KB scratch (Eb no longer needed)
  *(f32x4*)(red + t * 4) = acc_v;
  __syncthreads();
  {
    int h = t >> 5, d = t & 31, dqq = d >> 2, c = d & 3;
    float sum = 0.f;
#pragma unroll
    for (int rp = 0; rp < 4; ++rp)
      sum += red[(((h << 5) | (dqq << 2) | rp) << 2) + c];
    rescat[((size_t)(b * 1024 + i)) * 768 + h * 32 + d] = sum / sS[h];
  }
  {
    int h1 = wave, h2 = wave + 4, d2 = lane;
    size_t base = ((size_t)(b * 1024 + i)) * 768 + 256;
    rescat[base + h1 * 64 + d2] = acc_e0 / sS[h1];
    rescat[base + h2 * 64 + d2] = acc_e1 / sS[h2];
  }
}

// ---------------- kernel C: output projection ----------------------------
__global__ __launch_bounds__(256) void out_proj(
    const float* __restrict__ rescat, const float* __restrict__ Wo,
    const float* __restrict__ bo, float* __restrict__ out) {
  __shared__ __align__(16) float xs[8 * 768];
  int t = threadIdx.x;
  int row0 = blockIdx.x * 8;
#pragma unroll
  for (int p = 0; p < 6; ++p) {
    int f = p * 256 + t;
    *(f32x4*)(&xs[f * 4]) = *(const f32x4*)(rescat + (size_t)row0 * 768 + f * 4);
  }
  __syncthreads();
  float acc[8];
#pragma unroll
  for (int r = 0; r < 8; ++r) acc[r] = 0.f;
  for (int c = 0; c < 768; ++c) {
    float w = Wo[c * 256 + t];
#pragma unroll
    for (int r = 0; r < 8; ++r) acc[r] += xs[r * 768 + c] * w;
  }
  float bias = bo[t];
#pragma unroll
  for (int r = 0; r < 8; ++r)
    out[(size_t)(row0 + r) * 256 + t] = acc[r] + bias;
}

// ---------------- launch ---------------------------------------------------
extern "C" void kernel_launch(void* const* d_in, const int* in_sizes, int n_in,
                              void* d_out, int out_size, void* d_ws, size_t ws_size,
                              hipStream_t stream) {
  const float* node = (const float*)d_in[0];
  const float* edge = (const float*)d_in[1];
  const unsigned char* mask = (const unsigned char*)d_in[2];
  const float* Wq = (const float*)d_in[3];
  const float* Wk = (const float*)d_in[4];
  const float* Wv = (const float*)d_in[5];
  const float* We = (const float*)d_in[6];
  const float* be = (const float*)d_in[7];
  const float* Wo = (const float*)d_in[8];
  const float* bo = (const float*)d_in[9];

  float* ws = (float*)d_ws;
  float* qw = ws;                              // 524288 f32
  u16* kwb = (u16*)(ws + 524288);              // 524288 bf16
  u16* vwb = kwb + 524288;                     // 524288 bf16
  float* rescat = ws + 1048576;                // 1572864 f32
  float* mask_f = ws + 2621440;                // 2048 f32

  hipLaunchKernelGGL(mask_norm, dim3(1), dim3(256), 0, stream, mask, mask_f);
  hipLaunchKernelGGL(qkv_rope, dim3(256), dim3(256), 0, stream,
                     node, Wq, Wk, Wv, qw, kwb, vwb);
  hipLaunchKernelGGL(attn_fused, dim3(2048), dim3(256), 0, stream,
                     edge, qw, kwb, vwb, We, be, mask_f, rescat);
  hipLaunchKernelGGL(out_proj, dim3(256), dim3(256), 0, stream,
                     rescat, Wo, bo, (float*)d_out);
}